// Round 8
// baseline (167.222 us; speedup 1.0000x reference)
//
#include <hip/hip_runtime.h>

#define N_NODES 50000
#define N_EDGES 800000
#define NFEAT   256
#define NHID    128
#define NCLASS  47
#define H2P     48    // padded h2 row (bf16)
#define CSR_MAX (N_EDGES + 7 * N_NODES)   // every segment padded to multiple of 8
#define NSUB    8     // sub-bucketed degree counters (contention / NSUB)

typedef __attribute__((ext_vector_type(8))) short short8v;
typedef __attribute__((ext_vector_type(4))) float f32x4;

__device__ __forceinline__ ushort f2bf(float f) {
    unsigned u = __float_as_uint(f);
    unsigned r = (u + 0x7FFF + ((u >> 16) & 1)) >> 16;   // round-to-nearest-even
    return (ushort)r;
}
__device__ __forceinline__ float bf2f(ushort b) {
    return __uint_as_float(((unsigned)b) << 16);
}
__device__ __forceinline__ float blo(unsigned u) { return __uint_as_float(u << 16); }
__device__ __forceinline__ float bhi(unsigned u) { return __uint_as_float(u & 0xFFFF0000u); }

// ---------------- weight prep: transpose+convert W1, W2 to bf16 once ----------------

__global__ void wprep_kernel(const float* __restrict__ W1, const float* __restrict__ W2,
                             ushort* __restrict__ w1t, ushort* __restrict__ w2t) {
    int t = blockIdx.x * blockDim.x + threadIdx.x;
    if (t < NFEAT * NHID) {              // read coalesced over c-fast
        int k = t >> 7, c = t & 127;
        w1t[c * NFEAT + k] = f2bf(W1[(size_t)k * NHID + c]);
    }
    if (t < NHID * H2P) {
        int k = t / H2P, c = t % H2P;
        w2t[c * NHID + k] = (c < NCLASS) ? f2bf(W2[(size_t)k * NCLASS + c]) : 0;
    }
}

// ---------------- CSR build ----------------
// packed8[d*8+b]: high 24 bits = count, low 40 bits = sum(w) in 2^-20 fixed point.
// 8 sub-counters per node -> 8x more atomic address parallelism, chains of ~2.

__global__ void zero_init_kernel(unsigned long long* __restrict__ packed8,
                                 int2* __restrict__ csr, int* __restrict__ total) {
    int i = blockIdx.x * blockDim.x + threadIdx.x;
    if (i < CSR_MAX) csr[i] = make_int2(0, 0);   // src=0, w=+0.0f (pad entries)
    if (i < N_NODES * NSUB) packed8[i] = 0ull;
    if (i == 0) *total = 0;
}

__global__ void degcnt_kernel(const int* __restrict__ dst, const float* __restrict__ w,
                              unsigned long long* __restrict__ packed8,
                              int* __restrict__ pos, int E) {
    int e = blockIdx.x * blockDim.x + threadIdx.x;
    if (e >= E) return;
    int d = dst[e];
    int b = e & (NSUB - 1);
    unsigned fx = __float2uint_rn(w[e] * 1048576.0f);
    unsigned long long old = atomicAdd(&packed8[(size_t)d * NSUB + b],
                                       (1ull << 40) | (unsigned long long)fx);
    pos[e] = (int)(old >> 40);
}

// segment allocator + dinv: per node, sum 8 sub-counters (coalesced 64B read),
// block-local scan + one atomicAdd per block for the base. Node segments padded to 8.
__global__ __launch_bounds__(256) void segalloc_kernel(const unsigned long long* __restrict__ packed8,
                                                       int* __restrict__ counts,
                                                       float* __restrict__ dinv,
                                                       int* __restrict__ row_start,
                                                       int* __restrict__ sub_base,
                                                       int* __restrict__ total, int n) {
    __shared__ int s[256];
    __shared__ int base_s;
    int t = threadIdx.x;
    int i = blockIdx.x * 256 + t;
    int v = 0;
    if (i < n) {
        int cnt = 0;
        unsigned long long ws = 0;
        int sb[NSUB];
        #pragma unroll
        for (int b = 0; b < NSUB; ++b) {
            unsigned long long pk = packed8[(size_t)i * NSUB + b];
            sb[b] = cnt;
            cnt += (int)(pk >> 40);
            ws += (pk & 0xFFFFFFFFFFull);
        }
        counts[i] = cnt;
        float deg = 1.0f + (float)ws * (1.0f / 1048576.0f);
        dinv[i] = rsqrtf(deg);
        #pragma unroll
        for (int b = 0; b < NSUB; b += 4)
            *(int4*)&sub_base[(size_t)i * NSUB + b] = make_int4(sb[b], sb[b+1], sb[b+2], sb[b+3]);
        v = (cnt + 7) & ~7;
    }
    s[t] = v;
    __syncthreads();
    #pragma unroll
    for (int off = 1; off < 256; off <<= 1) {
        int x = s[t];
        if (t >= off) x += s[t - off];
        __syncthreads();
        s[t] = x;
        __syncthreads();
    }
    if (t == 255) base_s = atomicAdd(total, s[255]);
    __syncthreads();
    if (i < n) row_start[i] = base_s + s[t] - v;
}

// atomic-free scatter: slot = row_start[d] + sub_base[d][b] + pos[e]
__global__ void scatter_kernel(const int* __restrict__ src, const int* __restrict__ dst,
                               const float* __restrict__ w, const int* __restrict__ pos,
                               const float* __restrict__ dinv,
                               const int* __restrict__ row_start,
                               const int* __restrict__ sub_base,
                               int2* __restrict__ csr, int E) {
    int e = blockIdx.x * blockDim.x + threadIdx.x;
    if (e >= E) return;
    int d = dst[e], s = src[e];
    int b = e & (NSUB - 1);
    int p = row_start[d] + sub_base[(size_t)d * NSUB + b] + pos[e];
    int2 pr;
    pr.x = s;
    pr.y = __float_as_int(dinv[s] * w[e] * dinv[d]);
    csr[p] = pr;
}

// ---------------- Layer 1 GEMM (MFMA bf16): h1b = bf16(x @ W1) ----------------

__global__ __launch_bounds__(256) void gemm1_kernel(const float* __restrict__ x,
                                                    const ushort* __restrict__ w1t,
                                                    ushort* __restrict__ h1b) {
    __shared__ __align__(16) ushort xs[64][72];
    __shared__ __align__(16) ushort ws[128][72];
    int tid = threadIdx.x;
    int node0 = blockIdx.x * 64;
    int wave = tid >> 6, l = tid & 63;
    int fr = l & 15, fq = l >> 4;
    int r0 = (wave >> 1) * 32;
    int c0 = (wave & 1) * 64;

    f32x4 acc[2][4] = {};

    for (int kk0 = 0; kk0 < NFEAT; kk0 += 64) {
        // stage x tile (f32 -> bf16): coalesced float4 reads
        {
            int row = tid >> 2, q = tid & 3;
            int srow = node0 + row; if (srow >= N_NODES) srow = N_NODES - 1;
            const float4* src = (const float4*)(x + (size_t)srow * NFEAT + kk0 + q * 16);
            ushort tmp[16];
            #pragma unroll
            for (int i = 0; i < 4; ++i) {
                float4 v = src[i];
                tmp[i * 4 + 0] = f2bf(v.x); tmp[i * 4 + 1] = f2bf(v.y);
                tmp[i * 4 + 2] = f2bf(v.z); tmp[i * 4 + 3] = f2bf(v.w);
            }
            #pragma unroll
            for (int i = 0; i < 2; ++i)
                *(short8v*)&xs[row][q * 16 + i * 8] = *(short8v*)&tmp[i * 8];
        }
        // stage w1t tile: pure linear copy (no transpose, no convert)
        {
            int rr = tid >> 3;       // 0..31
            int cq = tid & 7;        // 16B chunk in the 128B k-span
            #pragma unroll
            for (int i = 0; i < 4; ++i) {
                int row = rr + i * 32;
                *(short8v*)&ws[row][cq * 8] =
                    *(const short8v*)&w1t[(size_t)row * NFEAT + kk0 + cq * 8];
            }
        }
        __syncthreads();
        short8v a[2][2], b[4][2];
        #pragma unroll
        for (int m = 0; m < 2; ++m)
            #pragma unroll
            for (int kf = 0; kf < 2; ++kf)
                a[m][kf] = *(const short8v*)&xs[r0 + m * 16 + fr][kf * 32 + fq * 8];
        #pragma unroll
        for (int n = 0; n < 4; ++n)
            #pragma unroll
            for (int kf = 0; kf < 2; ++kf)
                b[n][kf] = *(const short8v*)&ws[c0 + n * 16 + fr][kf * 32 + fq * 8];
        #pragma unroll
        for (int m = 0; m < 2; ++m)
            #pragma unroll
            for (int n = 0; n < 4; ++n)
                #pragma unroll
                for (int kf = 0; kf < 2; ++kf)
                    acc[m][n] = __builtin_amdgcn_mfma_f32_16x16x32_bf16(
                        a[m][kf], b[n][kf], acc[m][n], 0, 0, 0);
        __syncthreads();
    }
    #pragma unroll
    for (int m = 0; m < 2; ++m) {
        #pragma unroll
        for (int n = 0; n < 4; ++n) {
            #pragma unroll
            for (int j = 0; j < 4; ++j) {
                int gr = node0 + r0 + m * 16 + fq * 4 + j;
                if (gr < N_NODES)
                    h1b[(size_t)gr * NHID + c0 + n * 16 + fr] = f2bf(acc[m][n][j]);
            }
        }
    }
}

// ---------------- Aggregation 1: haggb = bf16(relu(A_norm @ h1 + b1)) ----------------
// one WAVE per node; lane = (half h, quarter q). Each lane gathers 8B (4 feats);
// the two 32-lane halves process 2 edges per instruction; 8 edges per iteration.

__global__ __launch_bounds__(256) void agg1_kernel(const ushort* __restrict__ h1b,
                                                   const int* __restrict__ row_start,
                                                   const int* __restrict__ counts,
                                                   const int2* __restrict__ csr,
                                                   const float* __restrict__ dinv,
                                                   const float* __restrict__ b1,
                                                   ushort* __restrict__ haggb) {
    int wv = threadIdx.x >> 6;
    int i = blockIdx.x * 4 + wv;
    int l = threadIdx.x & 63;
    int h = l >> 5, q = l & 31;
    const ushort* rowp = h1b + 4 * q;    // this lane's 4-feature slice

    float di = dinv[i];
    float sc = (h == 0) ? di * di : 0.f;
    uint2 sv = *(const uint2*)(rowp + (size_t)i * NHID);
    float4 acc;
    acc.x = sc * blo(sv.x); acc.y = sc * bhi(sv.x);
    acc.z = sc * blo(sv.y); acc.w = sc * bhi(sv.y);

    int lo = row_start[i], hi = lo + ((counts[i] + 7) & ~7);
    for (int e = lo; e < hi; e += 8) {
        int2 pA = csr[e + 0 + h];
        int2 pB = csr[e + 2 + h];
        int2 pC = csr[e + 4 + h];
        int2 pD = csr[e + 6 + h];
        uint2 vA = *(const uint2*)(rowp + (size_t)pA.x * NHID);
        uint2 vB = *(const uint2*)(rowp + (size_t)pB.x * NHID);
        uint2 vC = *(const uint2*)(rowp + (size_t)pC.x * NHID);
        uint2 vD = *(const uint2*)(rowp + (size_t)pD.x * NHID);
        float wA = __int_as_float(pA.y), wB = __int_as_float(pB.y);
        float wC = __int_as_float(pC.y), wD = __int_as_float(pD.y);
        acc.x = fmaf(wA, blo(vA.x), acc.x); acc.y = fmaf(wA, bhi(vA.x), acc.y);
        acc.z = fmaf(wA, blo(vA.y), acc.z); acc.w = fmaf(wA, bhi(vA.y), acc.w);
        acc.x = fmaf(wB, blo(vB.x), acc.x); acc.y = fmaf(wB, bhi(vB.x), acc.y);
        acc.z = fmaf(wB, blo(vB.y), acc.z); acc.w = fmaf(wB, bhi(vB.y), acc.w);
        acc.x = fmaf(wC, blo(vC.x), acc.x); acc.y = fmaf(wC, bhi(vC.x), acc.y);
        acc.z = fmaf(wC, blo(vC.y), acc.z); acc.w = fmaf(wC, bhi(vC.y), acc.w);
        acc.x = fmaf(wD, blo(vD.x), acc.x); acc.y = fmaf(wD, bhi(vD.x), acc.y);
        acc.z = fmaf(wD, blo(vD.y), acc.z); acc.w = fmaf(wD, bhi(vD.y), acc.w);
    }
    // combine the two halves
    acc.x += __shfl_xor(acc.x, 32);
    acc.y += __shfl_xor(acc.y, 32);
    acc.z += __shfl_xor(acc.z, 32);
    acc.w += __shfl_xor(acc.w, 32);
    if (h == 0) {
        float4 bb = *(const float4*)(b1 + 4 * q);
        acc.x = fmaxf(acc.x + bb.x, 0.f);
        acc.y = fmaxf(acc.y + bb.y, 0.f);
        acc.z = fmaxf(acc.z + bb.z, 0.f);
        acc.w = fmaxf(acc.w + bb.w, 0.f);
        uint2 o;
        o.x = (unsigned)f2bf(acc.x) | ((unsigned)f2bf(acc.y) << 16);
        o.y = (unsigned)f2bf(acc.z) | ((unsigned)f2bf(acc.w) << 16);
        *(uint2*)(haggb + (size_t)i * NHID + 4 * q) = o;
    }
}

// ---------------- Layer 2 GEMM (MFMA bf16): h2b = bf16(hagg @ W2), rows padded to 48 ----------------

__global__ __launch_bounds__(256) void gemm2_kernel(const ushort* __restrict__ haggb,
                                                    const ushort* __restrict__ w2t,
                                                    ushort* __restrict__ h2b) {
    __shared__ __align__(16) ushort ha[64][136];
    __shared__ __align__(16) ushort wt[48][136];
    int tid = threadIdx.x;
    int node0 = blockIdx.x * 64;
    {
        int row = tid >> 2, q = tid & 3;
        int srow = node0 + row; if (srow >= N_NODES) srow = N_NODES - 1;
        const short8v* src = (const short8v*)(haggb + (size_t)srow * NHID + q * 32);
        #pragma unroll
        for (int i = 0; i < 4; ++i)
            *(short8v*)&ha[row][q * 32 + i * 8] = src[i];
    }
    {   // stage w2t: pure linear copy, 768 x 16B chunks
        #pragma unroll
        for (int i = 0; i < 3; ++i) {
            int id = tid + i * 256;
            int row = id >> 4, cq = id & 15;
            *(short8v*)&wt[row][cq * 8] =
                *(const short8v*)&w2t[(size_t)row * NHID + cq * 8];
        }
    }
    __syncthreads();
    int wave = tid >> 6, l = tid & 63;
    int fr = l & 15, fq = l >> 4;
    int r0 = wave * 16;
    short8v a[4], b[3][4];
    #pragma unroll
    for (int kf = 0; kf < 4; ++kf)
        a[kf] = *(const short8v*)&ha[r0 + fr][kf * 32 + fq * 8];
    #pragma unroll
    for (int n = 0; n < 3; ++n)
        #pragma unroll
        for (int kf = 0; kf < 4; ++kf)
            b[n][kf] = *(const short8v*)&wt[n * 16 + fr][kf * 32 + fq * 8];
    f32x4 acc[3] = {};
    #pragma unroll
    for (int n = 0; n < 3; ++n)
        #pragma unroll
        for (int kf = 0; kf < 4; ++kf)
            acc[n] = __builtin_amdgcn_mfma_f32_16x16x32_bf16(a[kf], b[n][kf], acc[n], 0, 0, 0);
    #pragma unroll
    for (int n = 0; n < 3; ++n) {
        #pragma unroll
        for (int j = 0; j < 4; ++j) {
            int gr = node0 + r0 + fq * 4 + j;
            int col = n * 16 + fr;
            if (gr < N_NODES && col < H2P)
                h2b[(size_t)gr * H2P + col] = (col < NCLASS) ? f2bf(acc[n][j]) : 0;
        }
    }
}

// ---------------- Aggregation 2 + bias + log_softmax -> out ----------------

__global__ __launch_bounds__(256) void agg2_kernel(const ushort* __restrict__ h2b,
                                                   const int* __restrict__ row_start,
                                                   const int* __restrict__ counts,
                                                   const int2* __restrict__ csr,
                                                   const float* __restrict__ dinv,
                                                   const float* __restrict__ b2,
                                                   float* __restrict__ out, int n) {
    int wv = threadIdx.x >> 6;
    int i = blockIdx.x * 4 + wv;
    if (i >= n) return;
    int l = threadIdx.x & 63;
    int h = l >> 5, q = l & 31;
    bool act = q < 24;
    int qq = act ? q : 0;
    const ushort* rowp = h2b + 2 * qq;   // this lane's 2-feature slice

    float di = dinv[i];
    float sc = (h == 0 && act) ? di * di : 0.f;
    unsigned sv = *(const unsigned*)(rowp + (size_t)i * H2P);
    float2 acc;
    acc.x = sc * blo(sv); acc.y = sc * bhi(sv);

    int lo = row_start[i], hi = lo + ((counts[i] + 7) & ~7);
    for (int e = lo; e < hi; e += 8) {
        int2 pA = csr[e + 0 + h];
        int2 pB = csr[e + 2 + h];
        int2 pC = csr[e + 4 + h];
        int2 pD = csr[e + 6 + h];
        unsigned vA = *(const unsigned*)(rowp + (size_t)pA.x * H2P);
        unsigned vB = *(const unsigned*)(rowp + (size_t)pB.x * H2P);
        unsigned vC = *(const unsigned*)(rowp + (size_t)pC.x * H2P);
        unsigned vD = *(const unsigned*)(rowp + (size_t)pD.x * H2P);
        float wA = __int_as_float(pA.y), wB = __int_as_float(pB.y);
        float wC = __int_as_float(pC.y), wD = __int_as_float(pD.y);
        acc.x = fmaf(wA, blo(vA), acc.x); acc.y = fmaf(wA, bhi(vA), acc.y);
        acc.x = fmaf(wB, blo(vB), acc.x); acc.y = fmaf(wB, bhi(vB), acc.y);
        acc.x = fmaf(wC, blo(vC), acc.x); acc.y = fmaf(wC, bhi(vC), acc.y);
        acc.x = fmaf(wD, blo(vD), acc.x); acc.y = fmaf(wD, bhi(vD), acc.y);
    }
    acc.x += __shfl_xor(acc.x, 32);
    acc.y += __shfl_xor(acc.y, 32);

    // log-softmax over 47 classes held 2-per-lane in lanes 0-23 of each half
    float v0 = -1e30f, v1 = -1e30f;
    if (act) {
        v0 = acc.x + b2[2 * q];
        v1 = (2 * q + 1 < NCLASS) ? (acc.y + b2[2 * q + 1]) : -1e30f;
    }
    float pm = fmaxf(v0, v1);
    #pragma unroll
    for (int off = 16; off; off >>= 1) pm = fmaxf(pm, __shfl_xor(pm, off));
    float ex = 0.f;
    if (act) {
        ex = __expf(v0 - pm);
        if (2 * q + 1 < NCLASS) ex += __expf(v1 - pm);
    }
    #pragma unroll
    for (int off = 16; off; off >>= 1) ex += __shfl_xor(ex, off);
    if (h == 0 && act) {
        float ls = pm + __logf(ex);
        out[(size_t)i * NCLASS + 2 * q] = v0 - ls;
        if (2 * q + 1 < NCLASS) out[(size_t)i * NCLASS + 2 * q + 1] = v1 - ls;
    }
}

// ---------------- launch ----------------

extern "C" void kernel_launch(void* const* d_in, const int* in_sizes, int n_in,
                              void* d_out, int out_size, void* d_ws, size_t ws_size,
                              hipStream_t stream) {
    const float* x  = (const float*)d_in[0];
    const int*   ei = (const int*)d_in[1];
    const float* ew = (const float*)d_in[2];
    const float* W1 = (const float*)d_in[3];
    const float* b1 = (const float*)d_in[4];
    const float* W2 = (const float*)d_in[5];
    const float* b2 = (const float*)d_in[6];
    float* out = (float*)d_out;

    const int* e_src = ei;
    const int* e_dst = ei + N_EDGES;

    char* p = (char*)d_ws;
    auto carve = [&](size_t bytes) { void* r = (void*)p; p += (bytes + 255) & ~(size_t)255; return r; };
    unsigned long long* packed8 = (unsigned long long*)carve((size_t)N_NODES * NSUB * 8);
    float*  dinv      = (float*) carve(N_NODES * 4);
    int*    counts    = (int*)   carve(N_NODES * 4);
    int*    row_start = (int*)   carve(N_NODES * 4);
    int*    sub_base  = (int*)   carve((size_t)N_NODES * NSUB * 4);
    int*    total     = (int*)   carve(4);
    int*    pos       = (int*)   carve((size_t)N_EDGES * 4);
    int2*   csr       = (int2*)  carve((size_t)CSR_MAX * 8);
    ushort* h1b       = (ushort*)carve((size_t)N_NODES * NHID * 2);
    ushort* haggb     = (ushort*)carve((size_t)N_NODES * NHID * 2);
    ushort* h2b       = (ushort*)carve((size_t)N_NODES * H2P * 2);
    ushort* w1t       = (ushort*)carve((size_t)NHID * NFEAT * 2);
    ushort* w2t       = (ushort*)carve((size_t)H2P * NHID * 2);

    wprep_kernel<<<(NFEAT * NHID + 255) / 256, 256, 0, stream>>>(W1, W2, w1t, w2t);
    zero_init_kernel<<<(CSR_MAX + 255) / 256, 256, 0, stream>>>(packed8, csr, total);
    degcnt_kernel<<<(N_EDGES + 255) / 256, 256, 0, stream>>>(e_dst, ew, packed8, pos, N_EDGES);
    segalloc_kernel<<<(N_NODES + 255) / 256, 256, 0, stream>>>(packed8, counts, dinv,
                                                               row_start, sub_base, total, N_NODES);
    scatter_kernel<<<(N_EDGES + 255) / 256, 256, 0, stream>>>(e_src, e_dst, ew, pos, dinv,
                                                              row_start, sub_base, csr, N_EDGES);
    gemm1_kernel<<<(N_NODES + 63) / 64, 256, 0, stream>>>(x, w1t, h1b);
    agg1_kernel<<<(N_NODES + 3) / 4, 256, 0, stream>>>(h1b, row_start, counts, csr, dinv, b1, haggb);
    gemm2_kernel<<<(N_NODES + 63) / 64, 256, 0, stream>>>(haggb, w2t, h2b);
    agg2_kernel<<<(N_NODES + 3) / 4, 256, 0, stream>>>(h2b, row_start, counts, csr, dinv, b2, out, N_NODES);
}